// Round 2
// 215.882 us; speedup vs baseline: 1.0663x; 1.0663x over previous
//
#include <hip/hip_runtime.h>
#include <hip/hip_bf16.h>
#include <cstdint>

typedef __attribute__((ext_vector_type(8))) short short8;
typedef __attribute__((ext_vector_type(4))) float f32x4;

#define B_  2
#define S_  2048
#define D_  1024
#define H_  16
#define HD  64

static __device__ __forceinline__ float bf2f(unsigned int u16) {
    union { unsigned int i; float f; } v; v.i = u16 << 16; return v.f;
}
static __device__ __forceinline__ unsigned short f2bf(float f) {
    union { float f; unsigned int i; } v; v.f = f;
    unsigned int r = v.i + 0x7FFFu + ((v.i >> 16) & 1u);
    return (unsigned short)(r >> 16);
}
// pack two floats to bf16x2 (hi in top 16, lo in bottom)
static __device__ __forceinline__ unsigned pack_bf16(float hi, float lo) {
    union { float f; unsigned u; } h, l;
    h.f = hi; l.f = lo;
    return __builtin_amdgcn_perm(h.u + 0x8000u, l.u + 0x8000u, 0x07060302);
}
static __device__ __forceinline__ void load_lds_16B(const unsigned short* g, unsigned short* l) {
    __builtin_amdgcn_global_load_lds(
        (const __attribute__((address_space(1))) unsigned int*)g,
        (__attribute__((address_space(3))) unsigned int*)l, 16, 0, 0);
}

// ---------------- fp32 -> bf16 conversion ----------------
__global__ void cvt_f32_bf16(const float* __restrict__ src,
                             unsigned short* __restrict__ dst, int n4) {
    int i = blockIdx.x * 256 + threadIdx.x;
    if (i >= n4) return;
    float4 f = ((const float4*)src)[i];
    uint2 o;
    o.x = (unsigned int)f2bf(f.x) | ((unsigned int)f2bf(f.y) << 16);
    o.y = (unsigned int)f2bf(f.z) | ((unsigned int)f2bf(f.w) << 16);
    ((uint2*)dst)[i] = o;
}

// all 4 weights in one launch; dst regions contiguous (1M elems each)
__global__ void cvt_w4(const float* __restrict__ w0, const float* __restrict__ w1,
                       const float* __restrict__ w2, const float* __restrict__ w3,
                       unsigned short* __restrict__ dst) {
    int bid = blockIdx.x;                 // 0..4095
    int wsel = bid >> 10;
    const float* s = wsel == 0 ? w0 : wsel == 1 ? w1 : wsel == 2 ? w2 : w3;
    int i = (bid & 1023) * 256 + threadIdx.x;   // 0..262143
    float4 f = ((const float4*)s)[i];
    uint2 o;
    o.x = (unsigned int)f2bf(f.x) | ((unsigned int)f2bf(f.y) << 16);
    o.y = (unsigned int)f2bf(f.z) | ((unsigned int)f2bf(f.w) << 16);
    ((uint2*)dst)[(size_t)wsel * 262144 + i] = o;
}

// ---------------- fused QKV GEMM, m97-style 128x128 tile ----------------
__global__ __launch_bounds__(256) void qkv_gemm(
    const unsigned short* __restrict__ xbf,
    const unsigned short* __restrict__ wq,
    const unsigned short* __restrict__ wk,
    const unsigned short* __restrict__ wv,
    unsigned short* __restrict__ qb,
    unsigned short* __restrict__ kb,
    unsigned short* __restrict__ vb)
{
    __shared__ unsigned short As[128 * 32];
    __shared__ unsigned short Bs[128 * 32];

    const int tid  = threadIdx.x;
    const int w    = tid >> 6, lane = tid & 63;
    const int l15  = lane & 15, quad = lane >> 4;
    const int wrow = (w >> 1) * 64, wcol = (w & 1) * 64;

    const int m0 = blockIdx.x * 128;
    const int nc = blockIdx.y * 128;
    const int sel = nc >> 10;
    const int n0 = nc & 1023;
    const unsigned short* __restrict__ W = sel == 0 ? wq : (sel == 1 ? wk : wv);
    unsigned short* __restrict__ Out = sel == 0 ? qb : (sel == 1 ? kb : vb);

    const int lr = lane >> 2, lc = (lane & 3) * 8;
    const unsigned short* ga = xbf + (size_t)(m0 + w * 16 + lr) * 1024 + lc;
    const unsigned short* gb = W   + (size_t)(n0 + w * 16 + lr) * 1024 + lc;
    unsigned short* la0 = As + (w * 16) * 32;
    unsigned short* la1 = As + (64 + w * 16) * 32;
    unsigned short* lb0 = Bs + (w * 16) * 32;
    unsigned short* lb1 = Bs + (64 + w * 16) * 32;

    f32x4 acc[4][4] = {};

    for (int k0 = 0; k0 < 1024; k0 += 32) {
        __syncthreads();
        load_lds_16B(ga + k0,             la0);
        load_lds_16B(ga + 64 * 1024 + k0, la1);
        load_lds_16B(gb + k0,             lb0);
        load_lds_16B(gb + 64 * 1024 + k0, lb1);
        __syncthreads();

        short8 a[4], b[4];
#pragma unroll
        for (int i = 0; i < 4; i++)
            a[i] = *(const short8*)&As[(wrow + i * 16 + l15) * 32 + quad * 8];
#pragma unroll
        for (int j = 0; j < 4; j++)
            b[j] = *(const short8*)&Bs[(wcol + j * 16 + l15) * 32 + quad * 8];
#pragma unroll
        for (int i = 0; i < 4; i++)
#pragma unroll
            for (int j = 0; j < 4; j++)
                acc[i][j] = __builtin_amdgcn_mfma_f32_16x16x32_bf16(a[i], b[j], acc[i][j], 0, 0, 0);
    }

    // epilogue: scatter to [B,H,S,hd] bf16
#pragma unroll
    for (int i = 0; i < 4; i++) {
#pragma unroll
        for (int r = 0; r < 4; r++) {
            int m = m0 + wrow + i * 16 + quad * 4 + r;
            int bb = m >> 11, s = m & 2047;
#pragma unroll
            for (int j = 0; j < 4; j++) {
                int n = n0 + wcol + j * 16 + l15;
                int h = n >> 6, d = n & 63;
                Out[(((size_t)(bb * H_ + h) * S_) + s) * HD + d] = f2bf(acc[i][j][r]);
            }
        }
    }
}

// ---------------- output GEMM, same structure, fp32 out ----------------
__global__ __launch_bounds__(256) void out_gemm(
    const unsigned short* __restrict__ A,
    const unsigned short* __restrict__ Bt,
    float* __restrict__ C)
{
    __shared__ unsigned short As[128 * 32];
    __shared__ unsigned short Bs[128 * 32];

    const int tid  = threadIdx.x;
    const int w    = tid >> 6, lane = tid & 63;
    const int l15  = lane & 15, quad = lane >> 4;
    const int wrow = (w >> 1) * 64, wcol = (w & 1) * 64;

    const int m0 = blockIdx.x * 128;
    const int n0 = blockIdx.y * 128;

    const int lr = lane >> 2, lc = (lane & 3) * 8;
    const unsigned short* ga = A  + (size_t)(m0 + w * 16 + lr) * 1024 + lc;
    const unsigned short* gb = Bt + (size_t)(n0 + w * 16 + lr) * 1024 + lc;
    unsigned short* la0 = As + (w * 16) * 32;
    unsigned short* la1 = As + (64 + w * 16) * 32;
    unsigned short* lb0 = Bs + (w * 16) * 32;
    unsigned short* lb1 = Bs + (64 + w * 16) * 32;

    f32x4 acc[4][4] = {};

    for (int k0 = 0; k0 < 1024; k0 += 32) {
        __syncthreads();
        load_lds_16B(ga + k0,             la0);
        load_lds_16B(ga + 64 * 1024 + k0, la1);
        load_lds_16B(gb + k0,             lb0);
        load_lds_16B(gb + 64 * 1024 + k0, lb1);
        __syncthreads();

        short8 a[4], b[4];
#pragma unroll
        for (int i = 0; i < 4; i++)
            a[i] = *(const short8*)&As[(wrow + i * 16 + l15) * 32 + quad * 8];
#pragma unroll
        for (int j = 0; j < 4; j++)
            b[j] = *(const short8*)&Bs[(wcol + j * 16 + l15) * 32 + quad * 8];
#pragma unroll
        for (int i = 0; i < 4; i++)
#pragma unroll
            for (int j = 0; j < 4; j++)
                acc[i][j] = __builtin_amdgcn_mfma_f32_16x16x32_bf16(a[i], b[j], acc[i][j], 0, 0, 0);
    }

#pragma unroll
    for (int i = 0; i < 4; i++)
#pragma unroll
        for (int r = 0; r < 4; r++) {
            int m = m0 + wrow + i * 16 + quad * 4 + r;
#pragma unroll
            for (int j = 0; j < 4; j++)
                C[(size_t)m * 1024 + n0 + wcol + j * 16 + l15] = acc[i][j][r];
        }
}

// ---------------- RoPE on Q and K in [B,H,S,hd] bf16 ---------------------
__global__ void rope_qk(unsigned short* __restrict__ qb,
                        unsigned short* __restrict__ kb,
                        const float* __restrict__ fcos,
                        const float* __restrict__ fsin)
{
    int idx = blockIdx.x * 256 + threadIdx.x;
    int t  = idx & 31;
    int s  = (idx >> 5) & (S_ - 1);
    int bh = idx >> 16;
    float c  = fcos[s * 32 + t];
    float si = fsin[s * 32 + t];
    size_t off = ((size_t)bh * S_ + s) * HD + 2 * t;

    unsigned int* qp = (unsigned int*)(qb + off);
    unsigned int u = *qp;
    float r = bf2f(u & 0xffffu), im = bf2f(u >> 16);
    *qp = pack_bf16(im * c + r * si, r * c - im * si);

    unsigned int* kp = (unsigned int*)(kb + off);
    u = *kp;
    r = bf2f(u & 0xffffu); im = bf2f(u >> 16);
    *kp = pack_bf16(im * c + r * si, r * c - im * si);
}

// ---------------- V transpose: vb [bh][s][d] -> vT [bh][d][s] ------------
// One 64x64 tile per block; done ONCE instead of ~16.5x inside flash.
__global__ __launch_bounds__(256) void v_transpose(
    const unsigned short* __restrict__ vb,
    unsigned short* __restrict__ vT)
{
    __shared__ unsigned short T[64][72];
    const int bh = blockIdx.x;
    const int j0 = blockIdx.y * 64;
    const int tid = threadIdx.x;
    const int vdg = tid >> 5, vp = tid & 31;
    const unsigned short* vptr = vb + ((size_t)bh * S_ + j0 + 2 * vp) * HD + vdg * 8;
    uint4 v0 = *(const uint4*)vptr;
    uint4 v1 = *(const uint4*)(vptr + HD);
    const unsigned* a0 = (const unsigned*)&v0;
    const unsigned* a1 = (const unsigned*)&v1;
#pragma unroll
    for (int c = 0; c < 4; c++) {
        *(unsigned*)&T[vdg * 8 + 2 * c][2 * vp]     = __builtin_amdgcn_perm(a1[c], a0[c], 0x05040100);
        *(unsigned*)&T[vdg * 8 + 2 * c + 1][2 * vp] = __builtin_amdgcn_perm(a1[c], a0[c], 0x07060302);
    }
    __syncthreads();
    // write out the FULL 64x64 tile: 2 halves x (8 lanes/row x 8 shorts) x 32 rows
    const int d = tid >> 3, js = (tid & 7) * 8;
#pragma unroll
    for (int dd = 0; dd < 2; dd++) {
        short8 row = *(const short8*)&T[dd * 32 + d][js];
        *(short8*)(vT + ((size_t)bh * HD + dd * 32 + d) * S_ + j0 + js) = row;
    }
}

// ---------------- causal flash attention, MFMA ---------------------------
// (1) per-CU load-balanced qt mapping, (2) XOR-swizzled K staging/reads,
// (3) V^T staged via global_load_lds from pre-transposed vT (swizzled),
// (4) defer-max rescale (THR=8, scale-invariant).
__global__ __launch_bounds__(256) void flash_attn_mfma(
    const unsigned short* __restrict__ qb,
    const unsigned short* __restrict__ kb,
    const unsigned short* __restrict__ vT,
    unsigned short* __restrict__ attnc)
{
    // Ks rows 64B; read slot(bits4-5) ^= row bits(7-8).
    __shared__ __attribute__((aligned(1024))) unsigned short Ks[2][64][32];
    // Vt rows 128B; read slot(bits4-6) ^= row bits(7-9).
    __shared__ __attribute__((aligned(1024))) unsigned short Vt[64][64];
    __shared__ unsigned short Pls[4][16][72];

    const int bh   = blockIdx.x;
    // load-balance: per-CU resident set {j, 31-j, 8+j, 23-j} sums to 66 for all j.
    const int qtb  = blockIdx.y;
    const int jj = qtb & 7, mm = qtb >> 3;
    const int qt = (mm == 0) ? jj : (mm == 1) ? 31 - jj : (mm == 2) ? 8 + jj : 23 - jj;

    const int b    = bh >> 4, h = bh & 15;
    const int tid  = threadIdx.x;
    const int w    = tid >> 6;
    const int lane = tid & 63;
    const int l15  = lane & 15;
    const int quad = lane >> 4;

    const size_t bhS = (size_t)bh * S_;
    const unsigned short* __restrict__ vTb = vT + (size_t)bh * HD * S_;

    short8 qfrag[2];
    {
        const unsigned short* qp = qb + (bhS + qt * 64 + w * 16 + l15) * HD + quad * 8;
        qfrag[0] = *(const short8*)(qp);
        qfrag[1] = *(const short8*)(qp + 32);
    }

    // staging source swizzles (inverse of the read swizzle; LDS dest linear)
    const int ksrow  = lane >> 2;
    const int ksslot = (lane & 3) ^ ((lane >> 3) & 3);
    const int vsrow  = lane >> 3;
    const int vsslot = (lane & 7) ^ vsrow;

    // read-side constant swizzle pieces
    const int ckq = (quad ^ ((l15 >> 1) & 3)) << 4;  // K: slot XOR folded to bytes
    const int s7  = l15 & 7;                          // V: 3-bit row field

    f32x4 O[4] = {};
    float mrow = -INFINITY;
    float lrow = 0.0f;
    const float sc = 0.125f * 1.44269504f;

    for (int jt = 0; jt <= qt; jt++) {
        const int j0 = jt * 64;
        // ---- K tile: direct-to-LDS, swizzled source ----
        {
            const unsigned short* kg = kb + (bhS + j0 + w * 16 + ksrow) * HD + ksslot * 8;
            load_lds_16B(kg,      &Ks[0][w * 16][0]);
            load_lds_16B(kg + 32, &Ks[1][w * 16][0]);
        }
        // ---- V^T tile: direct-to-LDS, swizzled source ----
        {
            const unsigned short* vg = vTb + (size_t)(w * 16 + vsrow) * S_ + j0 + vsslot * 8;
            load_lds_16B(vg,          &Vt[w * 16][0]);
            load_lds_16B(vg + 8 * S_, &Vt[w * 16 + 8][0]);
        }
        __syncthreads();

        const bool diag  = (jt == qt);
        const int  nsub  = diag ? (w + 1) : 4;
        const int  kgmax = (nsub + 1) >> 1;

        // ---- S^T = K·Q^T ----
        f32x4 Sacc[4];
        float tmax = -INFINITY;
        for (int sub = 0; sub < nsub; sub++) {
            f32x4 s = {};
#pragma unroll
            for (int kh = 0; kh < 2; kh++) {
                int bo = ((sub * 16 + l15) << 6) + ckq;
                short8 kf = *(const short8*)((const char*)&Ks[kh][0][0] + bo);
                s = __builtin_amdgcn_mfma_f32_16x16x32_bf16(kf, qfrag[kh], s, 0, 0, 0);
            }
#pragma unroll
            for (int r = 0; r < 4; r++) {
                float v = s[r] * sc;
                if (diag && (sub * 16 + quad * 4 + r > w * 16 + l15)) v = -INFINITY;
                s[r] = v;
                tmax = fmaxf(tmax, v);
            }
            Sacc[sub] = s;
        }
        tmax = fmaxf(tmax, __shfl_xor(tmax, 16, 64));
        tmax = fmaxf(tmax, __shfl_xor(tmax, 32, 64));

        // ---- defer-max rescale (THR=8 in log2 domain; wave-uniform) ----
        if (__any(tmax > mrow + 8.0f)) {
            float mnew = fmaxf(mrow, tmax);
            float ccr  = __builtin_amdgcn_exp2f(mrow - mnew);
            lrow *= ccr;
#pragma unroll
            for (int r = 0; r < 4; r++) {
                float ccq = __shfl(ccr, quad * 4 + r, 64);
#pragma unroll
                for (int dt = 0; dt < 4; dt++) O[dt][r] *= ccq;
            }
            mrow = mnew;
        }

        float psum = 0.0f;
        for (int sub = 0; sub < nsub; sub++) {
            f32x4 s = Sacc[sub];
            float p0 = __builtin_amdgcn_exp2f(s[0] - mrow);
            float p1 = __builtin_amdgcn_exp2f(s[1] - mrow);
            float p2 = __builtin_amdgcn_exp2f(s[2] - mrow);
            float p3 = __builtin_amdgcn_exp2f(s[3] - mrow);
            psum += (p0 + p1) + (p2 + p3);
            uint2 pk;
            pk.x = pack_bf16(p1, p0);
            pk.y = pack_bf16(p3, p2);
            *(uint2*)&Pls[w][l15][sub * 16 + quad * 4] = pk;
        }
        if (diag) {
            for (int sub = nsub; sub < 2 * kgmax; sub++) {
                uint2 z; z.x = 0u; z.y = 0u;
                *(uint2*)&Pls[w][l15][sub * 16 + quad * 4] = z;
            }
        }
        psum += __shfl_xor(psum, 16, 64);
        psum += __shfl_xor(psum, 32, 64);
        lrow += psum;

        for (int kg = 0; kg < kgmax; kg++) {
            short8 pf = *(const short8*)&Pls[w][l15][kg * 32 + quad * 8];
#pragma unroll
            for (int dt = 0; dt < 4; dt++) {
                int row = dt * 16 + l15;
                int slot = (((kg << 2) | quad) ^ s7) << 4;
                short8 vf = *(const short8*)((const char*)&Vt[0][0] + (row << 7) + slot);
                O[dt] = __builtin_amdgcn_mfma_f32_16x16x32_bf16(pf, vf, O[dt], 0, 0, 0);
            }
        }
        __syncthreads();
    }

    float inv = 1.0f / lrow;
#pragma unroll
    for (int r = 0; r < 4; r++) {
        float invq = __shfl(inv, quad * 4 + r, 64);
        int qabs = qt * 64 + w * 16 + quad * 4 + r;
        unsigned short* op = attnc + (((size_t)b * S_ + qabs) * H_ + h) * HD + l15;
#pragma unroll
        for (int dt = 0; dt < 4; dt++)
            op[dt * 16] = f2bf(O[dt][r] * invq);
    }
}

// ---------------- launch ----------------
extern "C" void kernel_launch(void* const* d_in, const int* in_sizes, int n_in,
                              void* d_out, int out_size, void* d_ws, size_t ws_size,
                              hipStream_t stream) {
    const float* x    = (const float*)d_in[0];
    const float* fcos = (const float*)d_in[1];
    const float* fsin = (const float*)d_in[2];
    const float* Wq   = (const float*)d_in[3];
    const float* Wk   = (const float*)d_in[4];
    const float* Wv   = (const float*)d_in[5];
    const float* Wo   = (const float*)d_in[6];
    float* out = (float*)d_out;

    unsigned short* ws = (unsigned short*)d_ws;
    unsigned short* xbf = ws;                      // 4M elems
    unsigned short* wqb = xbf + 4096 * 1024;       // 1M each, contiguous
    unsigned short* wkb = wqb + 1024 * 1024;
    unsigned short* wvb = wkb + 1024 * 1024;
    unsigned short* wob = wvb + 1024 * 1024;
    unsigned short* qb  = wob + 1024 * 1024;
    unsigned short* kb  = qb + 4096 * 1024;
    unsigned short* vb  = kb + 4096 * 1024;
    unsigned short* attnc = vb + 4096 * 1024;
    // vT aliases xbf: xbf is dead after qkv_gemm; exactly 4M elems needed.
    unsigned short* vT = xbf;

    cvt_f32_bf16<<<4096, 256, 0, stream>>>(x, xbf, 4096 * 1024 / 4);
    cvt_w4<<<4096, 256, 0, stream>>>(Wq, Wk, Wv, Wo, wqb);

    qkv_gemm<<<dim3(32, 24), 256, 0, stream>>>(xbf, wqb, wkb, wvb, qb, kb, vb);

    v_transpose<<<dim3(32, 32), 256, 0, stream>>>(vb, vT);

    rope_qk<<<8192, 256, 0, stream>>>(qb, kb, fcos, fsin);

    flash_attn_mfma<<<dim3(32, 32), 256, 0, stream>>>(qb, kb, vT, attnc);

    out_gemm<<<dim3(32, 8), 256, 0, stream>>>(attnc, wob, out);
}